// Round 1
// baseline (925.027 us; speedup 1.0000x reference)
//
#include <hip/hip_runtime.h>
#include <hip/hip_bf16.h>
#include <math.h>

#define BATCH 8
#define LSEQ 2048
#define DIM 512
#define SK 40
#define NTOP 40

// ---------------- GEMM: C[m,n] = sum_k A[m,k] * W[n,k]  (A=x, row-major; W row-major) ----
#define BM 64
#define BN 64
#define BKD 32

__global__ __launch_bounds__(256) void gemm_qkv(
    const float* __restrict__ x,
    const float* __restrict__ Wq, const float* __restrict__ Wk, const float* __restrict__ Wv,
    float* __restrict__ Q, float* __restrict__ K, float* __restrict__ V)
{
    const float* W;
    float* C;
    if (blockIdx.z == 0)      { W = Wq; C = Q; }
    else if (blockIdx.z == 1) { W = Wk; C = K; }
    else                      { W = Wv; C = V; }

    __shared__ float As[BKD][BM];   // [k][m]
    __shared__ float Bs[BKD][BN];   // [k][n]

    const int tid  = threadIdx.x;
    const int row0 = blockIdx.x * BM;
    const int col0 = blockIdx.y * BN;
    const int ty   = tid >> 4;   // 0..15 (m dir)
    const int tx   = tid & 15;   // 0..15 (n dir)

    const int lrow = tid >> 3;   // 0..31
    const int lkq  = tid & 7;    // 0..7 -> k quad

    float acc[4][4] = {};

    for (int k0 = 0; k0 < DIM; k0 += BKD) {
        #pragma unroll
        for (int h = 0; h < 2; ++h) {
            const int arow = lrow + h * 32;
            float4 va = *reinterpret_cast<const float4*>(&x[(size_t)(row0 + arow) * DIM + k0 + lkq * 4]);
            As[lkq * 4 + 0][arow] = va.x;
            As[lkq * 4 + 1][arow] = va.y;
            As[lkq * 4 + 2][arow] = va.z;
            As[lkq * 4 + 3][arow] = va.w;
            float4 vb = *reinterpret_cast<const float4*>(&W[(size_t)(col0 + arow) * DIM + k0 + lkq * 4]);
            Bs[lkq * 4 + 0][arow] = vb.x;
            Bs[lkq * 4 + 1][arow] = vb.y;
            Bs[lkq * 4 + 2][arow] = vb.z;
            Bs[lkq * 4 + 3][arow] = vb.w;
        }
        __syncthreads();

        #pragma unroll
        for (int kk = 0; kk < BKD; ++kk) {
            float4 a4 = *reinterpret_cast<const float4*>(&As[kk][ty * 4]);
            float4 b4 = *reinterpret_cast<const float4*>(&Bs[kk][tx * 4]);
            float af[4] = {a4.x, a4.y, a4.z, a4.w};
            float bf[4] = {b4.x, b4.y, b4.z, b4.w};
            #pragma unroll
            for (int i = 0; i < 4; ++i)
                #pragma unroll
                for (int j = 0; j < 4; ++j)
                    acc[i][j] += af[i] * bf[j];
        }
        __syncthreads();
    }

    #pragma unroll
    for (int i = 0; i < 4; ++i) {
        float4 o = make_float4(acc[i][0], acc[i][1], acc[i][2], acc[i][3]);
        *reinterpret_cast<float4*>(&C[(size_t)(row0 + ty * 4 + i) * DIM + col0 + tx * 4]) = o;
    }
}

// ---------------- M[b,l] = max_s (Q_l . K_idx) - (1/L) * sum_s (Q_l . K_idx) -------------
__global__ __launch_bounds__(256) void compute_m(
    const float* __restrict__ Q, const float* __restrict__ K,
    const int* __restrict__ smp, float* __restrict__ M)
{
    const int wave = threadIdx.x >> 6;
    const int lane = threadIdx.x & 63;
    const int g = blockIdx.x * 4 + wave;       // 0..16383  == b*L + l
    const int l = g & (LSEQ - 1);
    const int b = g >> 11;

    const float* qr = Q + (size_t)g * DIM;
    float4 q0 = *reinterpret_cast<const float4*>(&qr[lane * 8]);
    float4 q1 = *reinterpret_cast<const float4*>(&qr[lane * 8 + 4]);

    float mx = -1e30f, sm = 0.0f;
    for (int s = 0; s < SK; ++s) {
        const int idx = smp[l * SK + s];
        const float* kr = K + ((size_t)b * LSEQ + idx) * DIM;
        float4 k0 = *reinterpret_cast<const float4*>(&kr[lane * 8]);
        float4 k1 = *reinterpret_cast<const float4*>(&kr[lane * 8 + 4]);
        float p = q0.x * k0.x + q0.y * k0.y + q0.z * k0.z + q0.w * k0.w
                + q1.x * k1.x + q1.y * k1.y + q1.z * k1.z + q1.w * k1.w;
        #pragma unroll
        for (int o = 32; o; o >>= 1) p += __shfl_xor(p, o, 64);
        mx = fmaxf(mx, p);
        sm += p;
    }
    if (lane == 0) M[g] = mx - sm * (1.0f / LSEQ);
}

// ---------------- per-batch top-40 of M ------------------------------------------------
__global__ __launch_bounds__(256) void topk_kernel(
    const float* __restrict__ M, int* __restrict__ topidx)
{
    const int b = blockIdx.x;
    __shared__ float vals[LSEQ];
    __shared__ float wv[4];
    __shared__ int   wi[4];
    const int tid  = threadIdx.x;
    const int lane = tid & 63;
    const int wave = tid >> 6;

    for (int i = tid; i < LSEQ; i += 256) vals[i] = M[b * LSEQ + i];
    __syncthreads();

    for (int t = 0; t < NTOP; ++t) {
        float bv = -1e30f;
        int   bi = -1;
        for (int i = tid; i < LSEQ; i += 256) {
            float v = vals[i];
            if (v > bv) { bv = v; bi = i; }
        }
        #pragma unroll
        for (int o = 32; o; o >>= 1) {
            float ov = __shfl_xor(bv, o, 64);
            int   oi = __shfl_xor(bi, o, 64);
            if (ov > bv || (ov == bv && oi != -1 && (oi < bi || bi == -1))) { bv = ov; bi = oi; }
        }
        if (lane == 0) { wv[wave] = bv; wi[wave] = bi; }
        __syncthreads();
        if (tid == 0) {
            float fv = wv[0]; int fi = wi[0];
            #pragma unroll
            for (int w = 1; w < 4; ++w)
                if (wv[w] > fv || (wv[w] == fv && wi[w] != -1 && (wi[w] < fi || fi == -1))) { fv = wv[w]; fi = wi[w]; }
            topidx[b * NTOP + t] = fi;
            vals[fi] = -1e30f;
        }
        __syncthreads();
    }
}

// ---------------- V mean: partial sums over 128-row chunks, then reduce -----------------
__global__ __launch_bounds__(256) void vmean_partial(
    const float* __restrict__ V, float* __restrict__ P)
{
    const int b = blockIdx.x, c = blockIdx.y;
    const int tid = threadIdx.x;
    #pragma unroll
    for (int dd = 0; dd < 2; ++dd) {
        const int d = tid + dd * 256;
        const float* vp = V + ((size_t)b * LSEQ + c * 128) * DIM + d;
        float s = 0.0f;
        for (int r = 0; r < 128; ++r) s += vp[(size_t)r * DIM];
        P[(size_t)(b * 16 + c) * DIM + d] = s;
    }
}

__global__ __launch_bounds__(256) void vmean_reduce(
    const float* __restrict__ P, float* __restrict__ vmean)
{
    const int b = blockIdx.x;
    const int tid = threadIdx.x;
    #pragma unroll
    for (int dd = 0; dd < 2; ++dd) {
        const int d = tid + dd * 256;
        float s = 0.0f;
        #pragma unroll
        for (int c = 0; c < 16; ++c) s += P[(size_t)(b * 16 + c) * DIM + d];
        vmean[b * DIM + d] = s * (1.0f / LSEQ);
    }
}

// ---------------- fill out with broadcast vmean ----------------------------------------
__global__ __launch_bounds__(256) void fill_out(
    const float4* __restrict__ vmean4, float4* __restrict__ out4)
{
    const int f = blockIdx.x * 256 + threadIdx.x;   // 8*2048*128 float4
    const int d4 = f & 127;
    const int b  = f >> 18;                          // f / (2048*128)
    out4[f] = vmean4[b * 128 + d4];
}

// ---------------- full attention for the selected 40 rows per batch ---------------------
__global__ __launch_bounds__(256) void att_kernel(
    const float* __restrict__ Q, const float* __restrict__ K, const float* __restrict__ V,
    const int* __restrict__ topidx, float* __restrict__ out)
{
    const int b = blockIdx.x / NTOP;
    const int u = blockIdx.x % NTOP;
    const int l0 = topidx[b * NTOP + u];

    __shared__ float p[LSEQ];
    __shared__ float redm[4];
    __shared__ float reds[4];

    const int tid  = threadIdx.x;
    const int lane = tid & 63;
    const int wave = tid >> 6;

    const float* qr = Q + ((size_t)b * LSEQ + l0) * DIM;
    float4 q0 = *reinterpret_cast<const float4*>(&qr[lane * 8]);
    float4 q1 = *reinterpret_cast<const float4*>(&qr[lane * 8 + 4]);

    const float scale = 0.044194173824159216f;  // 1/sqrt(512)

    // logits: wave w handles l in [w*512, w*512+512)
    for (int it = 0; it < 512; ++it) {
        const int l = wave * 512 + it;
        const float* kr = K + ((size_t)b * LSEQ + l) * DIM;
        float4 k0 = *reinterpret_cast<const float4*>(&kr[lane * 8]);
        float4 k1 = *reinterpret_cast<const float4*>(&kr[lane * 8 + 4]);
        float d = q0.x * k0.x + q0.y * k0.y + q0.z * k0.z + q0.w * k0.w
                + q1.x * k1.x + q1.y * k1.y + q1.z * k1.z + q1.w * k1.w;
        #pragma unroll
        for (int o = 32; o; o >>= 1) d += __shfl_xor(d, o, 64);
        if (lane == 0) p[l] = d * scale;
    }
    __syncthreads();

    // softmax over p[0..2047]
    float mx = -1e30f;
    for (int i = tid; i < LSEQ; i += 256) mx = fmaxf(mx, p[i]);
    #pragma unroll
    for (int o = 32; o; o >>= 1) mx = fmaxf(mx, __shfl_xor(mx, o, 64));
    if (lane == 0) redm[wave] = mx;
    __syncthreads();
    mx = fmaxf(fmaxf(redm[0], redm[1]), fmaxf(redm[2], redm[3]));

    float s = 0.0f;
    for (int i = tid; i < LSEQ; i += 256) {
        float e = __expf(p[i] - mx);
        s += e;
        p[i] = e;
    }
    #pragma unroll
    for (int o = 32; o; o >>= 1) s += __shfl_xor(s, o, 64);
    if (lane == 0) reds[wave] = s;
    __syncthreads();
    const float rec = 1.0f / (reds[0] + reds[1] + reds[2] + reds[3]);

    // upd[d] = sum_l p[l] * V[b,l,d]   (each thread: d = tid, tid+256)
    float s0 = 0.0f, s1 = 0.0f;
    const float* vp = V + (size_t)b * LSEQ * DIM;
    for (int l = 0; l < LSEQ; ++l) {
        const float w = p[l];
        s0 += w * vp[(size_t)l * DIM + tid];
        s1 += w * vp[(size_t)l * DIM + tid + 256];
    }
    float* orow = out + ((size_t)b * LSEQ + l0) * DIM;
    orow[tid]       = s0 * rec;
    orow[tid + 256] = s1 * rec;
}

// ---------------------------------------------------------------------------------------
extern "C" void kernel_launch(void* const* d_in, const int* in_sizes, int n_in,
                              void* d_out, int out_size, void* d_ws, size_t ws_size,
                              hipStream_t stream)
{
    const float* x   = (const float*)d_in[0];
    const float* Wq  = (const float*)d_in[1];
    const float* Wk  = (const float*)d_in[2];
    const float* Wv  = (const float*)d_in[3];
    const int*   smp = (const int*)d_in[4];
    float* out = (float*)d_out;

    const size_t NQKV = (size_t)BATCH * LSEQ * DIM;   // 8388608
    float* Q = (float*)d_ws;
    float* K = Q + NQKV;
    float* V = K + NQKV;
    float* M = V + NQKV;                              // 16384
    int*   topidx = (int*)(M + (size_t)BATCH * LSEQ); // 320 ints
    float* P = (float*)(topidx + BATCH * NTOP);       // 8*16*512 = 65536
    float* vmean = P + (size_t)BATCH * 16 * DIM;      // 4096

    dim3 g1(LSEQ * BATCH / BM, DIM / BN, 3);
    gemm_qkv<<<g1, 256, 0, stream>>>(x, Wq, Wk, Wv, Q, K, V);

    compute_m<<<BATCH * LSEQ / 4, 256, 0, stream>>>(Q, K, smp, M);

    topk_kernel<<<BATCH, 256, 0, stream>>>(M, topidx);

    vmean_partial<<<dim3(BATCH, 16), 256, 0, stream>>>(V, P);
    vmean_reduce<<<BATCH, 256, 0, stream>>>(P, vmean);

    fill_out<<<(BATCH * LSEQ * DIM / 4) / 256, 256, 0, stream>>>(
        (const float4*)vmean, (float4*)out);

    att_kernel<<<BATCH * NTOP, 256, 0, stream>>>(Q, K, V, topidx, out);
}

// Round 2
// 397.979 us; speedup vs baseline: 2.3243x; 2.3243x over previous
//
#include <hip/hip_runtime.h>
#include <hip/hip_bf16.h>
#include <math.h>

#define BATCH 8
#define LSEQ 2048
#define DIM 512
#define SK 40
#define NTOP 40

typedef __attribute__((ext_vector_type(8))) short bf16x8;
typedef __attribute__((ext_vector_type(4))) float f32x4;

// ---------------------------------------------------------------------------
// fp32 -> (hi, lo) bf16 split
__device__ inline void split1(float f, ushort& h, ushort& l) {
    __hip_bfloat16 bh = __float2bfloat16(f);
    float r = f - __bfloat162float(bh);
    __hip_bfloat16 bl = __float2bfloat16(r);
    h = *reinterpret_cast<ushort*>(&bh);
    l = *reinterpret_cast<ushort*>(&bl);
}

__global__ __launch_bounds__(256) void convert_x(
    const float* __restrict__ in, ushort* __restrict__ hi, ushort* __restrict__ lo)
{
    const int i = (blockIdx.x * 256 + threadIdx.x) * 4;
    float4 v = *reinterpret_cast<const float4*>(in + i);
    ushort4 h, l;
    split1(v.x, h.x, l.x); split1(v.y, h.y, l.y);
    split1(v.z, h.z, l.z); split1(v.w, h.w, l.w);
    *reinterpret_cast<ushort4*>(hi + i) = h;
    *reinterpret_cast<ushort4*>(lo + i) = l;
}

__global__ __launch_bounds__(256) void convert_w(
    const float* __restrict__ w0, const float* __restrict__ w1, const float* __restrict__ w2,
    ushort* __restrict__ hi, ushort* __restrict__ lo)
{
    const float* src = (blockIdx.z == 0) ? w0 : (blockIdx.z == 1) ? w1 : w2;
    ushort* h = hi + (size_t)blockIdx.z * DIM * DIM;
    ushort* l = lo + (size_t)blockIdx.z * DIM * DIM;
    const int i = (blockIdx.x * 256 + threadIdx.x) * 4;
    float4 v = *reinterpret_cast<const float4*>(src + i);
    ushort4 hh, ll;
    split1(v.x, hh.x, ll.x); split1(v.y, hh.y, ll.y);
    split1(v.z, hh.z, ll.z); split1(v.w, hh.w, ll.w);
    *reinterpret_cast<ushort4*>(h + i) = hh;
    *reinterpret_cast<ushort4*>(l + i) = ll;
}

// ---------------------------------------------------------------------------
// split-bf16 MFMA GEMM: C[m,n] = sum_k A[m,k]*W[n,k], 128x128 tile, BK=32
__device__ inline void load_lds16(const void* g, void* l) {
    __builtin_amdgcn_global_load_lds(
        (const __attribute__((address_space(1))) void*)g,
        (__attribute__((address_space(3))) void*)l, 16, 0, 0);
}

__global__ __launch_bounds__(256) void gemm_mfma(
    const ushort* __restrict__ xh, const ushort* __restrict__ xl,
    const ushort* __restrict__ whAll, const ushort* __restrict__ wlAll,
    float* __restrict__ Q, float* __restrict__ K, float* __restrict__ V)
{
    const ushort* Wh = whAll + (size_t)blockIdx.z * DIM * DIM;
    const ushort* Wl = wlAll + (size_t)blockIdx.z * DIM * DIM;
    float* C = (blockIdx.z == 0) ? Q : (blockIdx.z == 1) ? K : V;

    __shared__ ushort Ah[128 * 32], Al[128 * 32], Bh[128 * 32], Bl[128 * 32];

    const int tid  = threadIdx.x;
    const int lane = tid & 63;
    const int w    = tid >> 6;
    const int row0 = blockIdx.x * 128;
    const int col0 = blockIdx.y * 128;
    const int wr = w >> 1, wc = w & 1;

    // staging: chunk c covers rows c*64..c*64+63; wave w covers 16 rows in it.
    // LDS element offset for this lane: c*2048 + w*512 + lane*8 (HW adds lane*16B)
    // r = c*64 + w*16 + (lane>>2); slot = lane&3; source col-half = slot ^ ((r>>1)&3)
    const int rA  = w * 16 + (lane >> 2);
    const int sh_ = (lane & 3) ^ ((rA >> 1) & 3);
    const size_t aoff = (size_t)(row0 + rA) * DIM + sh_ * 8;
    const size_t boff = (size_t)(col0 + rA) * DIM + sh_ * 8;

    f32x4 acc[4][4];
    #pragma unroll
    for (int i = 0; i < 4; ++i)
        #pragma unroll
        for (int j = 0; j < 4; ++j)
            acc[i][j] = (f32x4){0.f, 0.f, 0.f, 0.f};

    const int rbA = wr * 64 + (lane & 15);
    const int rbB = wc * 64 + (lane & 15);
    const int kh  = lane >> 4;

    for (int k0 = 0; k0 < DIM; k0 += 32) {
        load_lds16(xh + aoff + k0,            &Ah[w * 512]);
        load_lds16(xh + aoff + 64 * DIM + k0, &Ah[2048 + w * 512]);
        load_lds16(xl + aoff + k0,            &Al[w * 512]);
        load_lds16(xl + aoff + 64 * DIM + k0, &Al[2048 + w * 512]);
        load_lds16(Wh + boff + k0,            &Bh[w * 512]);
        load_lds16(Wh + boff + 64 * DIM + k0, &Bh[2048 + w * 512]);
        load_lds16(Wl + boff + k0,            &Bl[w * 512]);
        load_lds16(Wl + boff + 64 * DIM + k0, &Bl[2048 + w * 512]);
        __syncthreads();

        bf16x8 fah[4], fal[4], fbh[4], fbl[4];
        #pragma unroll
        for (int mf = 0; mf < 4; ++mf) {
            const int r = rbA + mf * 16;
            const int off = r * 32 + (kh ^ ((r >> 1) & 3)) * 8;
            fah[mf] = *reinterpret_cast<const bf16x8*>(&Ah[off]);
            fal[mf] = *reinterpret_cast<const bf16x8*>(&Al[off]);
        }
        #pragma unroll
        for (int nf = 0; nf < 4; ++nf) {
            const int r = rbB + nf * 16;
            const int off = r * 32 + (kh ^ ((r >> 1) & 3)) * 8;
            fbh[nf] = *reinterpret_cast<const bf16x8*>(&Bh[off]);
            fbl[nf] = *reinterpret_cast<const bf16x8*>(&Bl[off]);
        }
        #pragma unroll
        for (int mf = 0; mf < 4; ++mf)
            #pragma unroll
            for (int nf = 0; nf < 4; ++nf) {
                acc[mf][nf] = __builtin_amdgcn_mfma_f32_16x16x32_bf16(fah[mf], fbh[nf], acc[mf][nf], 0, 0, 0);
                acc[mf][nf] = __builtin_amdgcn_mfma_f32_16x16x32_bf16(fal[mf], fbh[nf], acc[mf][nf], 0, 0, 0);
                acc[mf][nf] = __builtin_amdgcn_mfma_f32_16x16x32_bf16(fah[mf], fbl[nf], acc[mf][nf], 0, 0, 0);
            }
        __syncthreads();
    }

    #pragma unroll
    for (int mf = 0; mf < 4; ++mf)
        #pragma unroll
        for (int nf = 0; nf < 4; ++nf) {
            float* cp = C + (size_t)(row0 + wr * 64 + mf * 16 + (lane >> 4) * 4) * DIM
                          + col0 + wc * 64 + nf * 16 + (lane & 15);
            #pragma unroll
            for (int j = 0; j < 4; ++j)
                cp[(size_t)j * DIM] = acc[mf][nf][j];
        }
}

// ---------------------------------------------------------------------------
// fallback fp32 GEMM (round-1, proven)
#define BM 64
#define BN 64
#define BKD 32
__global__ __launch_bounds__(256) void gemm_qkv(
    const float* __restrict__ x,
    const float* __restrict__ Wq, const float* __restrict__ Wk, const float* __restrict__ Wv,
    float* __restrict__ Q, float* __restrict__ K, float* __restrict__ V)
{
    const float* W;
    float* C;
    if (blockIdx.z == 0)      { W = Wq; C = Q; }
    else if (blockIdx.z == 1) { W = Wk; C = K; }
    else                      { W = Wv; C = V; }

    __shared__ float As[BKD][BM];
    __shared__ float Bs[BKD][BN];

    const int tid  = threadIdx.x;
    const int row0 = blockIdx.x * BM;
    const int col0 = blockIdx.y * BN;
    const int ty   = tid >> 4;
    const int tx   = tid & 15;
    const int lrow = tid >> 3;
    const int lkq  = tid & 7;

    float acc[4][4] = {};
    for (int k0 = 0; k0 < DIM; k0 += BKD) {
        #pragma unroll
        for (int h = 0; h < 2; ++h) {
            const int arow = lrow + h * 32;
            float4 va = *reinterpret_cast<const float4*>(&x[(size_t)(row0 + arow) * DIM + k0 + lkq * 4]);
            As[lkq * 4 + 0][arow] = va.x; As[lkq * 4 + 1][arow] = va.y;
            As[lkq * 4 + 2][arow] = va.z; As[lkq * 4 + 3][arow] = va.w;
            float4 vb = *reinterpret_cast<const float4*>(&W[(size_t)(col0 + arow) * DIM + k0 + lkq * 4]);
            Bs[lkq * 4 + 0][arow] = vb.x; Bs[lkq * 4 + 1][arow] = vb.y;
            Bs[lkq * 4 + 2][arow] = vb.z; Bs[lkq * 4 + 3][arow] = vb.w;
        }
        __syncthreads();
        #pragma unroll
        for (int kk = 0; kk < BKD; ++kk) {
            float4 a4 = *reinterpret_cast<const float4*>(&As[kk][ty * 4]);
            float4 b4 = *reinterpret_cast<const float4*>(&Bs[kk][tx * 4]);
            float af[4] = {a4.x, a4.y, a4.z, a4.w};
            float bf[4] = {b4.x, b4.y, b4.z, b4.w};
            #pragma unroll
            for (int i = 0; i < 4; ++i)
                #pragma unroll
                for (int j = 0; j < 4; ++j)
                    acc[i][j] += af[i] * bf[j];
        }
        __syncthreads();
    }
    #pragma unroll
    for (int i = 0; i < 4; ++i) {
        float4 o = make_float4(acc[i][0], acc[i][1], acc[i][2], acc[i][3]);
        *reinterpret_cast<float4*>(&C[(size_t)(row0 + ty * 4 + i) * DIM + col0 + tx * 4]) = o;
    }
}

// ---------------------------------------------------------------------------
__global__ __launch_bounds__(256) void compute_m(
    const float* __restrict__ Q, const float* __restrict__ K,
    const int* __restrict__ smp, float* __restrict__ M)
{
    const int wave = threadIdx.x >> 6;
    const int lane = threadIdx.x & 63;
    const int g = blockIdx.x * 4 + wave;
    const int l = g & (LSEQ - 1);
    const int b = g >> 11;

    const float* qr = Q + (size_t)g * DIM;
    float4 q0 = *reinterpret_cast<const float4*>(&qr[lane * 8]);
    float4 q1 = *reinterpret_cast<const float4*>(&qr[lane * 8 + 4]);

    float mx = -1e30f, sm = 0.0f;
    #pragma unroll 2
    for (int s = 0; s < SK; ++s) {
        const int idx = smp[l * SK + s];
        const float* kr = K + ((size_t)b * LSEQ + idx) * DIM;
        float4 k0 = *reinterpret_cast<const float4*>(&kr[lane * 8]);
        float4 k1 = *reinterpret_cast<const float4*>(&kr[lane * 8 + 4]);
        float p = q0.x * k0.x + q0.y * k0.y + q0.z * k0.z + q0.w * k0.w
                + q1.x * k1.x + q1.y * k1.y + q1.z * k1.z + q1.w * k1.w;
        #pragma unroll
        for (int o = 32; o; o >>= 1) p += __shfl_xor(p, o, 64);
        mx = fmaxf(mx, p);
        sm += p;
    }
    if (lane == 0) M[g] = mx - sm * (1.0f / LSEQ);
}

__global__ __launch_bounds__(256) void topk_kernel(
    const float* __restrict__ M, int* __restrict__ topidx)
{
    const int b = blockIdx.x;
    __shared__ float vals[LSEQ];
    __shared__ float wv[4];
    __shared__ int   wi[4];
    const int tid  = threadIdx.x;
    const int lane = tid & 63;
    const int wave = tid >> 6;

    for (int i = tid; i < LSEQ; i += 256) vals[i] = M[b * LSEQ + i];
    __syncthreads();

    for (int t = 0; t < NTOP; ++t) {
        float bv = -1e30f;
        int   bi = -1;
        for (int i = tid; i < LSEQ; i += 256) {
            float v = vals[i];
            if (v > bv) { bv = v; bi = i; }
        }
        #pragma unroll
        for (int o = 32; o; o >>= 1) {
            float ov = __shfl_xor(bv, o, 64);
            int   oi = __shfl_xor(bi, o, 64);
            if (ov > bv || (ov == bv && oi != -1 && (oi < bi || bi == -1))) { bv = ov; bi = oi; }
        }
        if (lane == 0) { wv[wave] = bv; wi[wave] = bi; }
        __syncthreads();
        if (tid == 0) {
            float fv = wv[0]; int fi = wi[0];
            #pragma unroll
            for (int ww = 1; ww < 4; ++ww)
                if (wv[ww] > fv || (wv[ww] == fv && wi[ww] != -1 && (wi[ww] < fi || fi == -1))) { fv = wv[ww]; fi = wi[ww]; }
            topidx[b * NTOP + t] = fi;
            vals[fi] = -1e30f;
        }
        __syncthreads();
    }
}

__global__ __launch_bounds__(256) void vmean_partial(
    const float* __restrict__ V, float* __restrict__ P)
{
    const int b = blockIdx.x, c = blockIdx.y;
    const int tid = threadIdx.x;
    #pragma unroll
    for (int dd = 0; dd < 2; ++dd) {
        const int d = tid + dd * 256;
        const float* vp = V + ((size_t)b * LSEQ + c * 128) * DIM + d;
        float s = 0.0f;
        for (int r = 0; r < 128; ++r) s += vp[(size_t)r * DIM];
        P[(size_t)(b * 16 + c) * DIM + d] = s;
    }
}

__global__ __launch_bounds__(256) void vmean_reduce(
    const float* __restrict__ P, float* __restrict__ vmean)
{
    const int b = blockIdx.x;
    const int tid = threadIdx.x;
    #pragma unroll
    for (int dd = 0; dd < 2; ++dd) {
        const int d = tid + dd * 256;
        float s = 0.0f;
        #pragma unroll
        for (int c = 0; c < 16; ++c) s += P[(size_t)(b * 16 + c) * DIM + d];
        vmean[b * DIM + d] = s * (1.0f / LSEQ);
    }
}

__global__ __launch_bounds__(256) void fill_out(
    const float4* __restrict__ vmean4, float4* __restrict__ out4)
{
    const int f = blockIdx.x * 256 + threadIdx.x;
    const int d4 = f & 127;
    const int b  = f >> 18;
    out4[f] = vmean4[b * 128 + d4];
}

// ---------------------------------------------------------------------------
// new attention pipeline
__global__ __launch_bounds__(512) void qsel_gather(
    const float* __restrict__ Q, const int* __restrict__ topidx, float* __restrict__ Qsel)
{
    const int row = blockIdx.x;               // b*40+u
    const int b = row / NTOP;
    const int d = threadIdx.x;
    Qsel[(size_t)row * DIM + d] = Q[((size_t)b * LSEQ + topidx[row]) * DIM + d];
}

__global__ __launch_bounds__(256) void scores_kernel(
    const float* __restrict__ Qsel, const float* __restrict__ K, float* __restrict__ S)
{
    const int lc = blockIdx.x;                // 64-key chunk, 0..31
    const int b  = blockIdx.y;
    __shared__ float Qs[40 * 132];
    __shared__ float Ks[64 * 132];
    const int tid = threadIdx.x;
    const int lt  = tid & 31;
    const int ug  = tid >> 5;                 // 0..7; u = ug + i*8
    float acc[2][5] = {};

    for (int d0 = 0; d0 < DIM; d0 += 128) {
        for (int j = tid; j < 1280; j += 256) {       // 40 rows x 32 float4
            const int u = j >> 5, d4 = j & 31;
            *reinterpret_cast<float4*>(&Qs[u * 132 + d4 * 4]) =
                *reinterpret_cast<const float4*>(&Qsel[((size_t)(b * NTOP + u)) * DIM + d0 + d4 * 4]);
        }
        for (int j = tid; j < 2048; j += 256) {       // 64 rows x 32 float4
            const int l = j >> 5, d4 = j & 31;
            *reinterpret_cast<float4*>(&Ks[l * 132 + d4 * 4]) =
                *reinterpret_cast<const float4*>(&K[((size_t)b * LSEQ + lc * 64 + l) * DIM + d0 + d4 * 4]);
        }
        __syncthreads();
        for (int d4 = 0; d4 < 32; ++d4) {
            float4 ka = *reinterpret_cast<const float4*>(&Ks[lt * 132 + d4 * 4]);
            float4 kb = *reinterpret_cast<const float4*>(&Ks[(lt + 32) * 132 + d4 * 4]);
            #pragma unroll
            for (int i = 0; i < 5; ++i) {
                float4 q = *reinterpret_cast<const float4*>(&Qs[(ug + i * 8) * 132 + d4 * 4]);
                acc[0][i] += q.x * ka.x + q.y * ka.y + q.z * ka.z + q.w * ka.w;
                acc[1][i] += q.x * kb.x + q.y * kb.y + q.z * kb.z + q.w * kb.w;
            }
        }
        __syncthreads();
    }
    const float scale = 0.044194173824159216f;
    #pragma unroll
    for (int i = 0; i < 5; ++i) {
        const int u = ug + i * 8;
        S[((size_t)(b * NTOP + u)) * LSEQ + lc * 64 + lt]      = acc[0][i] * scale;
        S[((size_t)(b * NTOP + u)) * LSEQ + lc * 64 + lt + 32] = acc[1][i] * scale;
    }
}

__global__ __launch_bounds__(256) void softmax_kernel(
    const float* __restrict__ S, float* __restrict__ Pt)
{
    const int row = blockIdx.x;               // b*40+u
    const int b = row / NTOP, u = row % NTOP;
    __shared__ float red[4];
    const int tid  = threadIdx.x;
    const int lane = tid & 63;
    const int wave = tid >> 6;
    const float* sr = S + (size_t)row * LSEQ;

    float v[8];
    float mx = -1e30f;
    #pragma unroll
    for (int j = 0; j < 8; ++j) { v[j] = sr[tid + j * 256]; mx = fmaxf(mx, v[j]); }
    #pragma unroll
    for (int o = 32; o; o >>= 1) mx = fmaxf(mx, __shfl_xor(mx, o, 64));
    if (lane == 0) red[wave] = mx;
    __syncthreads();
    mx = fmaxf(fmaxf(red[0], red[1]), fmaxf(red[2], red[3]));
    __syncthreads();

    float s = 0.0f;
    #pragma unroll
    for (int j = 0; j < 8; ++j) { v[j] = __expf(v[j] - mx); s += v[j]; }
    #pragma unroll
    for (int o = 32; o; o >>= 1) s += __shfl_xor(s, o, 64);
    if (lane == 0) red[wave] = s;
    __syncthreads();
    const float rec = 1.0f / (red[0] + red[1] + red[2] + red[3]);

    #pragma unroll
    for (int j = 0; j < 8; ++j)
        Pt[((size_t)b * LSEQ + tid + j * 256) * NTOP + u] = v[j] * rec;
}

__global__ __launch_bounds__(512) void pv_partial(
    const float* __restrict__ Pt, const float* __restrict__ V, float* __restrict__ Ppart)
{
    const int lc = blockIdx.x;                // 0..15, 128 keys each
    const int b  = blockIdx.y;
    const int d  = threadIdx.x;               // 0..511
    float part[NTOP] = {};
    for (int l = 0; l < 128; ++l) {
        const float v = V[((size_t)b * LSEQ + lc * 128 + l) * DIM + d];
        const float* ps = Pt + ((size_t)b * LSEQ + lc * 128 + l) * NTOP;
        #pragma unroll
        for (int u = 0; u < NTOP; ++u) part[u] = fmaf(ps[u], v, part[u]);
    }
    #pragma unroll
    for (int u = 0; u < NTOP; ++u)
        Ppart[(((size_t)(b * 16 + lc)) * NTOP + u) * DIM + d] = part[u];
}

__global__ __launch_bounds__(512) void pv_reduce(
    const float* __restrict__ Ppart, const int* __restrict__ topidx, float* __restrict__ out)
{
    const int row = blockIdx.x;               // b*40+u
    const int b = row / NTOP, u = row % NTOP;
    const int d = threadIdx.x;
    float s = 0.0f;
    #pragma unroll
    for (int lc = 0; lc < 16; ++lc)
        s += Ppart[(((size_t)(b * 16 + lc)) * NTOP + u) * DIM + d];
    out[((size_t)b * LSEQ + topidx[row]) * DIM + d] = s;
}

// ---------------------------------------------------------------------------
// round-1 attention (fallback only)
__global__ __launch_bounds__(256) void att_kernel(
    const float* __restrict__ Q, const float* __restrict__ K, const float* __restrict__ V,
    const int* __restrict__ topidx, float* __restrict__ out)
{
    const int b = blockIdx.x / NTOP;
    const int u = blockIdx.x % NTOP;
    const int l0 = topidx[b * NTOP + u];

    __shared__ float p[LSEQ];
    __shared__ float redm[4];
    __shared__ float reds[4];

    const int tid  = threadIdx.x;
    const int lane = tid & 63;
    const int wave = tid >> 6;

    const float* qr = Q + ((size_t)b * LSEQ + l0) * DIM;
    float4 q0 = *reinterpret_cast<const float4*>(&qr[lane * 8]);
    float4 q1 = *reinterpret_cast<const float4*>(&qr[lane * 8 + 4]);
    const float scale = 0.044194173824159216f;

    for (int it = 0; it < 512; ++it) {
        const int l = wave * 512 + it;
        const float* kr = K + ((size_t)b * LSEQ + l) * DIM;
        float4 k0 = *reinterpret_cast<const float4*>(&kr[lane * 8]);
        float4 k1 = *reinterpret_cast<const float4*>(&kr[lane * 8 + 4]);
        float d = q0.x * k0.x + q0.y * k0.y + q0.z * k0.z + q0.w * k0.w
                + q1.x * k1.x + q1.y * k1.y + q1.z * k1.z + q1.w * k1.w;
        #pragma unroll
        for (int o = 32; o; o >>= 1) d += __shfl_xor(d, o, 64);
        if (lane == 0) p[l] = d * scale;
    }
    __syncthreads();

    float mx = -1e30f;
    for (int i = tid; i < LSEQ; i += 256) mx = fmaxf(mx, p[i]);
    #pragma unroll
    for (int o = 32; o; o >>= 1) mx = fmaxf(mx, __shfl_xor(mx, o, 64));
    if (lane == 0) redm[wave] = mx;
    __syncthreads();
    mx = fmaxf(fmaxf(redm[0], redm[1]), fmaxf(redm[2], redm[3]));

    float s = 0.0f;
    for (int i = tid; i < LSEQ; i += 256) {
        float e = __expf(p[i] - mx);
        s += e;
        p[i] = e;
    }
    #pragma unroll
    for (int o = 32; o; o >>= 1) s += __shfl_xor(s, o, 64);
    if (lane == 0) reds[wave] = s;
    __syncthreads();
    const float rec = 1.0f / (reds[0] + reds[1] + reds[2] + reds[3]);

    float s0 = 0.0f, s1 = 0.0f;
    const float* vp = V + (size_t)b * LSEQ * DIM;
    for (int l = 0; l < LSEQ; ++l) {
        const float w = p[l];
        s0 += w * vp[(size_t)l * DIM + tid];
        s1 += w * vp[(size_t)l * DIM + tid + 256];
    }
    float* orow = out + ((size_t)b * LSEQ + l0) * DIM;
    orow[tid]       = s0 * rec;
    orow[tid + 256] = s1 * rec;
}

// ---------------------------------------------------------------------------
extern "C" void kernel_launch(void* const* d_in, const int* in_sizes, int n_in,
                              void* d_out, int out_size, void* d_ws, size_t ws_size,
                              hipStream_t stream)
{
    const float* x   = (const float*)d_in[0];
    const float* Wq  = (const float*)d_in[1];
    const float* Wk  = (const float*)d_in[2];
    const float* Wv  = (const float*)d_in[3];
    const int*   smp = (const int*)d_in[4];
    float* out = (float*)d_out;

    const size_t NQKV = (size_t)BATCH * LSEQ * DIM;   // 8388608
    float* ws = (float*)d_ws;

    // fast/mid layout
    float* Q     = ws;
    float* K     = Q + NQKV;
    float* V     = K + NQKV;
    float* Mb    = V + NQKV;                 // 16384
    float* vmP   = Mb + BATCH * LSEQ;        // 65536
    float* vmean = vmP + BATCH * 16 * DIM;   // 4096
    float* S     = vmean + BATCH * DIM;      // 655360
    float* Pt    = S + (size_t)BATCH * NTOP * LSEQ;   // 655360
    float* Qsel  = Pt + (size_t)BATCH * NTOP * LSEQ;  // 163840
    float* Ppart = Qsel + (size_t)BATCH * NTOP * DIM; // 2621440
    int*   topidx = (int*)(Ppart + (size_t)BATCH * 16 * NTOP * DIM);
    ushort* xh = (ushort*)(topidx + BATCH * NTOP);
    ushort* xl = xh + NQKV;
    ushort* wh = xl + NQKV;
    ushort* wl = wh + (size_t)3 * DIM * DIM;
    const size_t need_fast = (size_t)((char*)(wl + (size_t)3 * DIM * DIM) - (char*)d_ws);
    const size_t need_mid  = (size_t)((char*)(topidx + BATCH * NTOP) - (char*)d_ws);

    const bool fast = ws_size >= need_fast;
    const bool mid  = ws_size >= need_mid;

    if (mid) {
        if (fast) {
            convert_x<<<NQKV / 1024, 256, 0, stream>>>(x, xh, xl);
            convert_w<<<dim3(DIM * DIM / 1024, 1, 3), 256, 0, stream>>>(Wq, Wk, Wv, wh, wl);
            gemm_mfma<<<dim3(BATCH * LSEQ / 128, DIM / 128, 3), 256, 0, stream>>>(
                xh, xl, wh, wl, Q, K, V);
        } else {
            gemm_qkv<<<dim3(BATCH * LSEQ / BM, DIM / BN, 3), 256, 0, stream>>>(
                x, Wq, Wk, Wv, Q, K, V);
        }
        compute_m<<<BATCH * LSEQ / 4, 256, 0, stream>>>(Q, K, smp, Mb);
        topk_kernel<<<BATCH, 256, 0, stream>>>(Mb, topidx);
        vmean_partial<<<dim3(BATCH, 16), 256, 0, stream>>>(V, vmP);
        vmean_reduce<<<BATCH, 256, 0, stream>>>(vmP, vmean);
        fill_out<<<(BATCH * LSEQ * DIM / 4) / 256, 256, 0, stream>>>(
            (const float4*)vmean, (float4*)out);
        qsel_gather<<<BATCH * NTOP, 512, 0, stream>>>(Q, topidx, Qsel);
        scores_kernel<<<dim3(32, BATCH), 256, 0, stream>>>(Qsel, K, S);
        softmax_kernel<<<BATCH * NTOP, 256, 0, stream>>>(S, Pt);
        pv_partial<<<dim3(16, BATCH), 512, 0, stream>>>(Pt, V, Ppart);
        pv_reduce<<<BATCH * NTOP, 512, 0, stream>>>(Ppart, topidx, out);
    } else {
        // round-1 fallback layout + pipeline (needs ~96 MB, proven)
        float* Qf = ws;
        float* Kf = Qf + NQKV;
        float* Vf = Kf + NQKV;
        float* Mf = Vf + NQKV;
        int*   ti = (int*)(Mf + (size_t)BATCH * LSEQ);
        float* Pf = (float*)(ti + BATCH * NTOP);
        float* vm = Pf + (size_t)BATCH * 16 * DIM;

        gemm_qkv<<<dim3(BATCH * LSEQ / BM, DIM / BN, 3), 256, 0, stream>>>(
            x, Wq, Wk, Wv, Qf, Kf, Vf);
        compute_m<<<BATCH * LSEQ / 4, 256, 0, stream>>>(Qf, Kf, smp, Mf);
        topk_kernel<<<BATCH, 256, 0, stream>>>(Mf, ti);
        vmean_partial<<<dim3(BATCH, 16), 256, 0, stream>>>(Vf, Pf);
        vmean_reduce<<<BATCH, 256, 0, stream>>>(Pf, vm);
        fill_out<<<(BATCH * LSEQ * DIM / 4) / 256, 256, 0, stream>>>(
            (const float4*)vm, (float4*)out);
        att_kernel<<<BATCH * NTOP, 256, 0, stream>>>(Qf, Kf, Vf, ti, out);
    }
}

// Round 3
// 321.394 us; speedup vs baseline: 2.8782x; 1.2383x over previous
//
#include <hip/hip_runtime.h>
#include <hip/hip_bf16.h>
#include <math.h>

#define BATCH 8
#define LSEQ 2048
#define DIM 512
#define SK 40
#define NTOP 40

typedef __attribute__((ext_vector_type(8))) short bf16x8;
typedef __attribute__((ext_vector_type(4))) float f32x4;

// ---------------------------------------------------------------------------
// fp32 -> (hi, lo) bf16 split
__device__ inline void split1(float f, ushort& h, ushort& l) {
    __hip_bfloat16 bh = __float2bfloat16(f);
    float r = f - __bfloat162float(bh);
    __hip_bfloat16 bl = __float2bfloat16(r);
    h = *reinterpret_cast<ushort*>(&bh);
    l = *reinterpret_cast<ushort*>(&bl);
}

// one kernel: blocks [0,8192) convert x, blocks [8192,8960) convert the 3 W
__global__ __launch_bounds__(256) void convert_all(
    const float* __restrict__ x,
    const float* __restrict__ w0, const float* __restrict__ w1, const float* __restrict__ w2,
    ushort* __restrict__ xh, ushort* __restrict__ xl,
    ushort* __restrict__ wh, ushort* __restrict__ wl)
{
    const int bx = blockIdx.x;
    const float* src;
    ushort *dh, *dl;
    int i;
    if (bx < 8192) {
        i = (bx * 256 + (int)threadIdx.x) * 4;
        src = x; dh = xh; dl = xl;
    } else {
        const int j = bx - 8192;
        const int z = j >> 8;
        src = (z == 0) ? w0 : (z == 1) ? w1 : w2;
        dh = wh + (size_t)z * DIM * DIM;
        dl = wl + (size_t)z * DIM * DIM;
        i = ((j & 255) * 256 + (int)threadIdx.x) * 4;
    }
    float4 v = *reinterpret_cast<const float4*>(src + i);
    ushort4 h, l;
    split1(v.x, h.x, l.x); split1(v.y, h.y, l.y);
    split1(v.z, h.z, l.z); split1(v.w, h.w, l.w);
    *reinterpret_cast<ushort4*>(dh + i) = h;
    *reinterpret_cast<ushort4*>(dl + i) = l;
}

// ---------------------------------------------------------------------------
// split-bf16 MFMA GEMM: C[m,n] = sum_k A[m,k]*W[n,k], 128x128 tile, BK=32
__device__ inline void load_lds16(const void* g, void* l) {
    __builtin_amdgcn_global_load_lds(
        (const __attribute__((address_space(1))) void*)g,
        (__attribute__((address_space(3))) void*)l, 16, 0, 0);
}

__global__ __launch_bounds__(256) void gemm_mfma(
    const ushort* __restrict__ xh, const ushort* __restrict__ xl,
    const ushort* __restrict__ whAll, const ushort* __restrict__ wlAll,
    float* __restrict__ Q, float* __restrict__ K, float* __restrict__ V)
{
    const ushort* Wh = whAll + (size_t)blockIdx.z * DIM * DIM;
    const ushort* Wl = wlAll + (size_t)blockIdx.z * DIM * DIM;
    float* C = (blockIdx.z == 0) ? Q : (blockIdx.z == 1) ? K : V;

    __shared__ ushort Ah[128 * 32], Al[128 * 32], Bh[128 * 32], Bl[128 * 32];

    const int tid  = threadIdx.x;
    const int lane = tid & 63;
    const int w    = tid >> 6;
    const int row0 = blockIdx.x * 128;
    const int col0 = blockIdx.y * 128;
    const int wr = w >> 1, wc = w & 1;

    const int rA  = w * 16 + (lane >> 2);
    const int sh_ = (lane & 3) ^ ((rA >> 1) & 3);
    const size_t aoff = (size_t)(row0 + rA) * DIM + sh_ * 8;
    const size_t boff = (size_t)(col0 + rA) * DIM + sh_ * 8;

    f32x4 acc[4][4];
    #pragma unroll
    for (int i = 0; i < 4; ++i)
        #pragma unroll
        for (int j = 0; j < 4; ++j)
            acc[i][j] = (f32x4){0.f, 0.f, 0.f, 0.f};

    const int rbA = wr * 64 + (lane & 15);
    const int rbB = wc * 64 + (lane & 15);
    const int kh  = lane >> 4;

    for (int k0 = 0; k0 < DIM; k0 += 32) {
        load_lds16(xh + aoff + k0,            &Ah[w * 512]);
        load_lds16(xh + aoff + 64 * DIM + k0, &Ah[2048 + w * 512]);
        load_lds16(xl + aoff + k0,            &Al[w * 512]);
        load_lds16(xl + aoff + 64 * DIM + k0, &Al[2048 + w * 512]);
        load_lds16(Wh + boff + k0,            &Bh[w * 512]);
        load_lds16(Wh + boff + 64 * DIM + k0, &Bh[2048 + w * 512]);
        load_lds16(Wl + boff + k0,            &Bl[w * 512]);
        load_lds16(Wl + boff + 64 * DIM + k0, &Bl[2048 + w * 512]);
        __syncthreads();

        bf16x8 fah[4], fal[4], fbh[4], fbl[4];
        #pragma unroll
        for (int mf = 0; mf < 4; ++mf) {
            const int r = rbA + mf * 16;
            const int off = r * 32 + (kh ^ ((r >> 1) & 3)) * 8;
            fah[mf] = *reinterpret_cast<const bf16x8*>(&Ah[off]);
            fal[mf] = *reinterpret_cast<const bf16x8*>(&Al[off]);
        }
        #pragma unroll
        for (int nf = 0; nf < 4; ++nf) {
            const int r = rbB + nf * 16;
            const int off = r * 32 + (kh ^ ((r >> 1) & 3)) * 8;
            fbh[nf] = *reinterpret_cast<const bf16x8*>(&Bh[off]);
            fbl[nf] = *reinterpret_cast<const bf16x8*>(&Bl[off]);
        }
        #pragma unroll
        for (int mf = 0; mf < 4; ++mf)
            #pragma unroll
            for (int nf = 0; nf < 4; ++nf) {
                acc[mf][nf] = __builtin_amdgcn_mfma_f32_16x16x32_bf16(fah[mf], fbh[nf], acc[mf][nf], 0, 0, 0);
                acc[mf][nf] = __builtin_amdgcn_mfma_f32_16x16x32_bf16(fal[mf], fbh[nf], acc[mf][nf], 0, 0, 0);
                acc[mf][nf] = __builtin_amdgcn_mfma_f32_16x16x32_bf16(fah[mf], fbl[nf], acc[mf][nf], 0, 0, 0);
            }
        __syncthreads();
    }

    #pragma unroll
    for (int mf = 0; mf < 4; ++mf)
        #pragma unroll
        for (int nf = 0; nf < 4; ++nf) {
            float* cp = C + (size_t)(row0 + wr * 64 + mf * 16 + (lane >> 4) * 4) * DIM
                          + col0 + wc * 64 + nf * 16 + (lane & 15);
            #pragma unroll
            for (int j = 0; j < 4; ++j)
                cp[(size_t)j * DIM] = acc[mf][nf][j];
        }
}

// ---------------------------------------------------------------------------
// fallback fp32 GEMM (round-1, proven)
#define BM 64
#define BN 64
#define BKD 32
__global__ __launch_bounds__(256) void gemm_qkv(
    const float* __restrict__ x,
    const float* __restrict__ Wq, const float* __restrict__ Wk, const float* __restrict__ Wv,
    float* __restrict__ Q, float* __restrict__ K, float* __restrict__ V)
{
    const float* W;
    float* C;
    if (blockIdx.z == 0)      { W = Wq; C = Q; }
    else if (blockIdx.z == 1) { W = Wk; C = K; }
    else                      { W = Wv; C = V; }

    __shared__ float As[BKD][BM];
    __shared__ float Bs[BKD][BN];

    const int tid  = threadIdx.x;
    const int row0 = blockIdx.x * BM;
    const int col0 = blockIdx.y * BN;
    const int ty   = tid >> 4;
    const int tx   = tid & 15;
    const int lrow = tid >> 3;
    const int lkq  = tid & 7;

    float acc[4][4] = {};
    for (int k0 = 0; k0 < DIM; k0 += BKD) {
        #pragma unroll
        for (int h = 0; h < 2; ++h) {
            const int arow = lrow + h * 32;
            float4 va = *reinterpret_cast<const float4*>(&x[(size_t)(row0 + arow) * DIM + k0 + lkq * 4]);
            As[lkq * 4 + 0][arow] = va.x; As[lkq * 4 + 1][arow] = va.y;
            As[lkq * 4 + 2][arow] = va.z; As[lkq * 4 + 3][arow] = va.w;
            float4 vb = *reinterpret_cast<const float4*>(&W[(size_t)(col0 + arow) * DIM + k0 + lkq * 4]);
            Bs[lkq * 4 + 0][arow] = vb.x; Bs[lkq * 4 + 1][arow] = vb.y;
            Bs[lkq * 4 + 2][arow] = vb.z; Bs[lkq * 4 + 3][arow] = vb.w;
        }
        __syncthreads();
        #pragma unroll
        for (int kk = 0; kk < BKD; ++kk) {
            float4 a4 = *reinterpret_cast<const float4*>(&As[kk][ty * 4]);
            float4 b4 = *reinterpret_cast<const float4*>(&Bs[kk][tx * 4]);
            float af[4] = {a4.x, a4.y, a4.z, a4.w};
            float bf[4] = {b4.x, b4.y, b4.z, b4.w};
            #pragma unroll
            for (int i = 0; i < 4; ++i)
                #pragma unroll
                for (int j = 0; j < 4; ++j)
                    acc[i][j] += af[i] * bf[j];
        }
        __syncthreads();
    }
    #pragma unroll
    for (int i = 0; i < 4; ++i) {
        float4 o = make_float4(acc[i][0], acc[i][1], acc[i][2], acc[i][3]);
        *reinterpret_cast<float4*>(&C[(size_t)(row0 + ty * 4 + i) * DIM + col0 + tx * 4]) = o;
    }
}

// ---------------------------------------------------------------------------
// M[b,l] = max_s - mean_s of sampled dots. XCD-local: b = blockIdx.x & 7 so
// batch b's blocks land on XCD b (round-robin dispatch) and K[b] (4MB) stays
// in that XCD's L2. 4 waves/block, wave = one l, s unrolled by 4.
__global__ __launch_bounds__(256) void compute_m(
    const float* __restrict__ Q, const float* __restrict__ K,
    const int* __restrict__ smp, float* __restrict__ M)
{
    const int wv   = threadIdx.x >> 6;
    const int lane = threadIdx.x & 63;
    const int b    = blockIdx.x & 7;
    const int l    = (blockIdx.x >> 3) * 4 + wv;

    const float* qr = Q + ((size_t)b * LSEQ + l) * DIM;
    float4 q0 = *reinterpret_cast<const float4*>(&qr[lane * 8]);
    float4 q1 = *reinterpret_cast<const float4*>(&qr[lane * 8 + 4]);

    const int* sp = smp + l * SK;
    const float* Kb = K + (size_t)b * LSEQ * DIM;

    float mx = -1e30f, sm = 0.0f;
    for (int s = 0; s < SK; s += 4) {
        int4 id = *reinterpret_cast<const int4*>(sp + s);
        const float* r0 = Kb + (size_t)id.x * DIM + lane * 8;
        const float* r1 = Kb + (size_t)id.y * DIM + lane * 8;
        const float* r2 = Kb + (size_t)id.z * DIM + lane * 8;
        const float* r3 = Kb + (size_t)id.w * DIM + lane * 8;
        float4 a0 = *reinterpret_cast<const float4*>(r0);
        float4 a1 = *reinterpret_cast<const float4*>(r0 + 4);
        float4 b0 = *reinterpret_cast<const float4*>(r1);
        float4 b1 = *reinterpret_cast<const float4*>(r1 + 4);
        float4 c0 = *reinterpret_cast<const float4*>(r2);
        float4 c1 = *reinterpret_cast<const float4*>(r2 + 4);
        float4 d0 = *reinterpret_cast<const float4*>(r3);
        float4 d1 = *reinterpret_cast<const float4*>(r3 + 4);

        float p0 = q0.x*a0.x + q0.y*a0.y + q0.z*a0.z + q0.w*a0.w
                 + q1.x*a1.x + q1.y*a1.y + q1.z*a1.z + q1.w*a1.w;
        float p1 = q0.x*b0.x + q0.y*b0.y + q0.z*b0.z + q0.w*b0.w
                 + q1.x*b1.x + q1.y*b1.y + q1.z*b1.z + q1.w*b1.w;
        float p2 = q0.x*c0.x + q0.y*c0.y + q0.z*c0.z + q0.w*c0.w
                 + q1.x*c1.x + q1.y*c1.y + q1.z*c1.z + q1.w*c1.w;
        float p3 = q0.x*d0.x + q0.y*d0.y + q0.z*d0.z + q0.w*d0.w
                 + q1.x*d1.x + q1.y*d1.y + q1.z*d1.z + q1.w*d1.w;
        #pragma unroll
        for (int o = 32; o; o >>= 1) {
            p0 += __shfl_xor(p0, o, 64);
            p1 += __shfl_xor(p1, o, 64);
            p2 += __shfl_xor(p2, o, 64);
            p3 += __shfl_xor(p3, o, 64);
        }
        mx = fmaxf(mx, fmaxf(fmaxf(p0, p1), fmaxf(p2, p3)));
        sm += (p0 + p1) + (p2 + p3);
    }
    if (lane == 0) M[(size_t)b * LSEQ + l] = mx - sm * (1.0f / LSEQ);
}

// ---------------------------------------------------------------------------
__global__ __launch_bounds__(1024) void topk_kernel(
    const float* __restrict__ M, int* __restrict__ topidx)
{
    const int b = blockIdx.x;
    __shared__ float vals[LSEQ];
    __shared__ float wv[16];
    __shared__ int   wi[16];
    const int tid  = threadIdx.x;
    const int lane = tid & 63;
    const int wave = tid >> 6;

    vals[tid]        = M[b * LSEQ + tid];
    vals[tid + 1024] = M[b * LSEQ + tid + 1024];
    __syncthreads();

    for (int t = 0; t < NTOP; ++t) {
        float v0 = vals[tid], v1 = vals[tid + 1024];
        float bv; int bi;
        if (v0 >= v1) { bv = v0; bi = tid; } else { bv = v1; bi = tid + 1024; }
        #pragma unroll
        for (int o = 32; o; o >>= 1) {
            float ov = __shfl_xor(bv, o, 64);
            int   oi = __shfl_xor(bi, o, 64);
            if (ov > bv || (ov == bv && oi < bi)) { bv = ov; bi = oi; }
        }
        if (lane == 0) { wv[wave] = bv; wi[wave] = bi; }
        __syncthreads();
        if (wave == 0) {
            float fv = (lane < 16) ? wv[lane] : -1e30f;
            int   fi = (lane < 16) ? wi[lane] : 0x7fffffff;
            #pragma unroll
            for (int o = 8; o; o >>= 1) {
                float ov = __shfl_xor(fv, o, 64);
                int   oi = __shfl_xor(fi, o, 64);
                if (ov > fv || (ov == fv && oi < fi)) { fv = ov; fi = oi; }
            }
            if (lane == 0) {
                topidx[b * NTOP + t] = fi;
                vals[fi] = -1e30f;
            }
        }
        __syncthreads();
    }
}

__global__ __launch_bounds__(256) void vmean_partial(
    const float* __restrict__ V, float* __restrict__ P)
{
    const int b = blockIdx.x & 7, c = blockIdx.x >> 3;
    const int tid = threadIdx.x;
    #pragma unroll
    for (int dd = 0; dd < 2; ++dd) {
        const int d = tid + dd * 256;
        const float* vp = V + ((size_t)b * LSEQ + c * 128) * DIM + d;
        float s = 0.0f;
        for (int r = 0; r < 128; ++r) s += vp[(size_t)r * DIM];
        P[(size_t)(b * 16 + c) * DIM + d] = s;
    }
}

__global__ __launch_bounds__(256) void vmean_reduce(
    const float* __restrict__ P, float* __restrict__ vmean)
{
    const int b = blockIdx.x;
    const int tid = threadIdx.x;
    #pragma unroll
    for (int dd = 0; dd < 2; ++dd) {
        const int d = tid + dd * 256;
        float s = 0.0f;
        #pragma unroll
        for (int c = 0; c < 16; ++c) s += P[(size_t)(b * 16 + c) * DIM + d];
        vmean[b * DIM + d] = s * (1.0f / LSEQ);
    }
}

__global__ __launch_bounds__(256) void fill_out(
    const float4* __restrict__ vmean4, float4* __restrict__ out4)
{
    const int f = blockIdx.x * 256 + threadIdx.x;
    const int d4 = f & 127;
    const int b  = f >> 18;
    out4[f] = vmean4[b * 128 + d4];
}

// ---------------------------------------------------------------------------
// scores: gathers Q[topidx] rows itself (no Qsel buffer). XCD-local b = bx&7.
__global__ __launch_bounds__(256) void scores_kernel(
    const float* __restrict__ Q, const float* __restrict__ K,
    const int* __restrict__ topidx, float* __restrict__ S)
{
    const int b  = blockIdx.x & 7;
    const int lc = blockIdx.x >> 3;           // 64-key chunk, 0..31
    __shared__ float Qs[40 * 132];
    __shared__ float Ks[64 * 132];
    __shared__ int tix[NTOP];
    const int tid = threadIdx.x;
    const int lt  = tid & 31;
    const int ug  = tid >> 5;
    float acc[2][5] = {};

    if (tid < NTOP) tix[tid] = topidx[b * NTOP + tid];
    __syncthreads();

    for (int d0 = 0; d0 < DIM; d0 += 128) {
        for (int j = tid; j < 1280; j += 256) {
            const int u = j >> 5, d4 = j & 31;
            *reinterpret_cast<float4*>(&Qs[u * 132 + d4 * 4]) =
                *reinterpret_cast<const float4*>(&Q[((size_t)b * LSEQ + tix[u]) * DIM + d0 + d4 * 4]);
        }
        for (int j = tid; j < 2048; j += 256) {
            const int l = j >> 5, d4 = j & 31;
            *reinterpret_cast<float4*>(&Ks[l * 132 + d4 * 4]) =
                *reinterpret_cast<const float4*>(&K[((size_t)b * LSEQ + lc * 64 + l) * DIM + d0 + d4 * 4]);
        }
        __syncthreads();
        for (int d4 = 0; d4 < 32; ++d4) {
            float4 ka = *reinterpret_cast<const float4*>(&Ks[lt * 132 + d4 * 4]);
            float4 kb = *reinterpret_cast<const float4*>(&Ks[(lt + 32) * 132 + d4 * 4]);
            #pragma unroll
            for (int i = 0; i < 5; ++i) {
                float4 q = *reinterpret_cast<const float4*>(&Qs[(ug + i * 8) * 132 + d4 * 4]);
                acc[0][i] += q.x * ka.x + q.y * ka.y + q.z * ka.z + q.w * ka.w;
                acc[1][i] += q.x * kb.x + q.y * kb.y + q.z * kb.z + q.w * kb.w;
            }
        }
        __syncthreads();
    }
    const float scale = 0.044194173824159216f;
    #pragma unroll
    for (int i = 0; i < 5; ++i) {
        const int u = ug + i * 8;
        S[((size_t)(b * NTOP + u)) * LSEQ + lc * 64 + lt]      = acc[0][i] * scale;
        S[((size_t)(b * NTOP + u)) * LSEQ + lc * 64 + lt + 32] = acc[1][i] * scale;
    }
}

__global__ __launch_bounds__(256) void softmax_kernel(
    const float* __restrict__ S, float* __restrict__ Pt)
{
    const int row = blockIdx.x;
    const int b = row / NTOP, u = row % NTOP;
    __shared__ float red[4];
    const int tid  = threadIdx.x;
    const int lane = tid & 63;
    const int wave = tid >> 6;
    const float* sr = S + (size_t)row * LSEQ;

    float v[8];
    float mx = -1e30f;
    #pragma unroll
    for (int j = 0; j < 8; ++j) { v[j] = sr[tid + j * 256]; mx = fmaxf(mx, v[j]); }
    #pragma unroll
    for (int o = 32; o; o >>= 1) mx = fmaxf(mx, __shfl_xor(mx, o, 64));
    if (lane == 0) red[wave] = mx;
    __syncthreads();
    mx = fmaxf(fmaxf(red[0], red[1]), fmaxf(red[2], red[3]));
    __syncthreads();

    float s = 0.0f;
    #pragma unroll
    for (int j = 0; j < 8; ++j) { v[j] = __expf(v[j] - mx); s += v[j]; }
    #pragma unroll
    for (int o = 32; o; o >>= 1) s += __shfl_xor(s, o, 64);
    if (lane == 0) red[wave] = s;
    __syncthreads();
    const float rec = 1.0f / (red[0] + red[1] + red[2] + red[3]);

    #pragma unroll
    for (int j = 0; j < 8; ++j)
        Pt[((size_t)b * LSEQ + tid + j * 256) * NTOP + u] = v[j] * rec;
}

__global__ __launch_bounds__(512) void pv_partial(
    const float* __restrict__ Pt, const float* __restrict__ V, float* __restrict__ Ppart)
{
    const int b  = blockIdx.x & 7;
    const int lc = blockIdx.x >> 3;           // 0..15, 128 keys each
    const int d  = threadIdx.x;
    float part[NTOP] = {};
    for (int l = 0; l < 128; ++l) {
        const float v = V[((size_t)b * LSEQ + lc * 128 + l) * DIM + d];
        const float* ps = Pt + ((size_t)b * LSEQ + lc * 128 + l) * NTOP;
        #pragma unroll
        for (int u = 0; u < NTOP; ++u) part[u] = fmaf(ps[u], v, part[u]);
    }
    #pragma unroll
    for (int u = 0; u < NTOP; ++u)
        Ppart[(((size_t)(b * 16 + lc)) * NTOP + u) * DIM + d] = part[u];
}

__global__ __launch_bounds__(512) void pv_reduce(
    const float* __restrict__ Ppart, const int* __restrict__ topidx, float* __restrict__ out)
{
    const int row = blockIdx.x;
    const int b = row / NTOP, u = row % NTOP;
    const int d = threadIdx.x;
    float s = 0.0f;
    #pragma unroll
    for (int lc = 0; lc < 16; ++lc)
        s += Ppart[(((size_t)(b * 16 + lc)) * NTOP + u) * DIM + d];
    out[((size_t)b * LSEQ + topidx[row]) * DIM + d] = s;
}

// ---------------------------------------------------------------------------
// round-1 attention (fallback only)
__global__ __launch_bounds__(256) void att_kernel(
    const float* __restrict__ Q, const float* __restrict__ K, const float* __restrict__ V,
    const int* __restrict__ topidx, float* __restrict__ out)
{
    const int b = blockIdx.x / NTOP;
    const int u = blockIdx.x % NTOP;
    const int l0 = topidx[b * NTOP + u];

    __shared__ float p[LSEQ];
    __shared__ float redm[4];
    __shared__ float reds[4];

    const int tid  = threadIdx.x;
    const int lane = tid & 63;
    const int wave = tid >> 6;

    const float* qr = Q + ((size_t)b * LSEQ + l0) * DIM;
    float4 q0 = *reinterpret_cast<const float4*>(&qr[lane * 8]);
    float4 q1 = *reinterpret_cast<const float4*>(&qr[lane * 8 + 4]);
    const float scale = 0.044194173824159216f;

    for (int it = 0; it < 512; ++it) {
        const int l = wave * 512 + it;
        const float* kr = K + ((size_t)b * LSEQ + l) * DIM;
        float4 k0 = *reinterpret_cast<const float4*>(&kr[lane * 8]);
        float4 k1 = *reinterpret_cast<const float4*>(&kr[lane * 8 + 4]);
        float d = q0.x * k0.x + q0.y * k0.y + q0.z * k0.z + q0.w * k0.w
                + q1.x * k1.x + q1.y * k1.y + q1.z * k1.z + q1.w * k1.w;
        #pragma unroll
        for (int o = 32; o; o >>= 1) d += __shfl_xor(d, o, 64);
        if (lane == 0) p[l] = d * scale;
    }
    __syncthreads();

    float mx = -1e30f;
    for (int i = tid; i < LSEQ; i += 256) mx = fmaxf(mx, p[i]);
    #pragma unroll
    for (int o = 32; o; o >>= 1) mx = fmaxf(mx, __shfl_xor(mx, o, 64));
    if (lane == 0) redm[wave] = mx;
    __syncthreads();
    mx = fmaxf(fmaxf(redm[0], redm[1]), fmaxf(redm[2], redm[3]));

    float s = 0.0f;
    for (int i = tid; i < LSEQ; i += 256) {
        float e = __expf(p[i] - mx);
        s += e;
        p[i] = e;
    }
    #pragma unroll
    for (int o = 32; o; o >>= 1) s += __shfl_xor(s, o, 64);
    if (lane == 0) reds[wave] = s;
    __syncthreads();
    const float rec = 1.0f / (reds[0] + reds[1] + reds[2] + reds[3]);

    float s0 = 0.0f, s1 = 0.0f;
    const float* vp = V + (size_t)b * LSEQ * DIM;
    for (int l = 0; l < LSEQ; ++l) {
        const float w = p[l];
        s0 += w * vp[(size_t)l * DIM + tid];
        s1 += w * vp[(size_t)l * DIM + tid + 256];
    }
    float* orow = out + ((size_t)b * LSEQ + l0) * DIM;
    orow[tid]       = s0 * rec;
    orow[tid + 256] = s1 * rec;
}

// ---------------------------------------------------------------------------
extern "C" void kernel_launch(void* const* d_in, const int* in_sizes, int n_in,
                              void* d_out, int out_size, void* d_ws, size_t ws_size,
                              hipStream_t stream)
{
    const float* x   = (const float*)d_in[0];
    const float* Wq  = (const float*)d_in[1];
    const float* Wk  = (const float*)d_in[2];
    const float* Wv  = (const float*)d_in[3];
    const int*   smp = (const int*)d_in[4];
    float* out = (float*)d_out;

    const size_t NQKV = (size_t)BATCH * LSEQ * DIM;   // 8388608
    float* ws = (float*)d_ws;

    float* Q     = ws;
    float* K     = Q + NQKV;
    float* V     = K + NQKV;
    float* Mb    = V + NQKV;                 // 16384
    float* vmP   = Mb + BATCH * LSEQ;        // 65536
    float* vmean = vmP + BATCH * 16 * DIM;   // 4096
    float* S     = vmean + BATCH * DIM;      // 655360
    float* Pt    = S + (size_t)BATCH * NTOP * LSEQ;   // 655360
    float* Qsel  = Pt + (size_t)BATCH * NTOP * LSEQ;  // 163840 (reserved)
    float* Ppart = Qsel + (size_t)BATCH * NTOP * DIM; // 2621440
    int*   topidx = (int*)(Ppart + (size_t)BATCH * 16 * NTOP * DIM);
    ushort* xh = (ushort*)(topidx + BATCH * NTOP);
    ushort* xl = xh + NQKV;
    ushort* wh = xl + NQKV;
    ushort* wl = wh + (size_t)3 * DIM * DIM;
    const size_t need_fast = (size_t)((char*)(wl + (size_t)3 * DIM * DIM) - (char*)d_ws);
    const size_t need_mid  = (size_t)((char*)(topidx + BATCH * NTOP) - (char*)d_ws);

    const bool fast = ws_size >= need_fast;
    const bool mid  = ws_size >= need_mid;

    if (mid) {
        if (fast) {
            convert_all<<<8960, 256, 0, stream>>>(x, Wq, Wk, Wv, xh, xl, wh, wl);
            gemm_mfma<<<dim3(BATCH * LSEQ / 128, DIM / 128, 3), 256, 0, stream>>>(
                xh, xl, wh, wl, Q, K, V);
        } else {
            gemm_qkv<<<dim3(BATCH * LSEQ / BM, DIM / BN, 3), 256, 0, stream>>>(
                x, Wq, Wk, Wv, Q, K, V);
        }
        compute_m<<<4096, 256, 0, stream>>>(Q, K, smp, Mb);
        topk_kernel<<<BATCH, 1024, 0, stream>>>(Mb, topidx);
        vmean_partial<<<BATCH * 16, 256, 0, stream>>>(V, vmP);
        vmean_reduce<<<BATCH, 256, 0, stream>>>(vmP, vmean);
        fill_out<<<(BATCH * LSEQ * DIM / 4) / 256, 256, 0, stream>>>(
            (const float4*)vmean, (float4*)out);
        scores_kernel<<<256, 256, 0, stream>>>(Q, K, topidx, S);
        softmax_kernel<<<BATCH * NTOP, 256, 0, stream>>>(S, Pt);
        pv_partial<<<128, 512, 0, stream>>>(Pt, V, Ppart);
        pv_reduce<<<BATCH * NTOP, 512, 0, stream>>>(Ppart, topidx, out);
    } else {
        float* Qf = ws;
        float* Kf = Qf + NQKV;
        float* Vf = Kf + NQKV;
        float* Mf = Vf + NQKV;
        int*   ti = (int*)(Mf + (size_t)BATCH * LSEQ);
        float* Pf = (float*)(ti + BATCH * NTOP);
        float* vm = Pf + (size_t)BATCH * 16 * DIM;

        gemm_qkv<<<dim3(BATCH * LSEQ / BM, DIM / BN, 3), 256, 0, stream>>>(
            x, Wq, Wk, Wv, Qf, Kf, Vf);
        compute_m<<<4096, 256, 0, stream>>>(Qf, Kf, smp, Mf);
        topk_kernel<<<BATCH, 1024, 0, stream>>>(Mf, ti);
        vmean_partial<<<BATCH * 16, 256, 0, stream>>>(Vf, Pf);
        vmean_reduce<<<BATCH, 256, 0, stream>>>(Pf, vm);
        fill_out<<<(BATCH * LSEQ * DIM / 4) / 256, 256, 0, stream>>>(
            (const float4*)vm, (float4*)out);
        att_kernel<<<BATCH * NTOP, 256, 0, stream>>>(Qf, Kf, Vf, ti, out);
    }
}